// Round 6
// baseline (103.719 us; speedup 1.0000x reference)
//
#include <hip/hip_runtime.h>
#include <hip/hip_cooperative_groups.h>
#include <limits.h>

namespace cg = cooperative_groups;

#define HB 16
#define HH 96
#define HW 96
#define HN (HH*HW)
#define WPR 3                   // u32 words per mask row
#define WPI (HH*WPR)            // 288 words per image mask
#define STRIPES 12
#define ROWS_PER (HH/STRIPES)   // 8 rows per stripe
#define PX_PER (ROWS_PER*HW)    // 768 px per stripe
#define TPB 256
#define NBLK (HB*STRIPES)       // 192 blocks

// nearest |x - x'| over set bits of a 96-bit row (lo = bits 0..63, hi = 64..95).
// Row must be non-empty; result <= 95. (Verified absmax=0 in R2-R4.)
__device__ __forceinline__ int nearest_dx(unsigned long long lo, unsigned int hi, int x) {
    int dr = 1 << 20, dl = 1 << 20;
    if (x < 64) {
        unsigned long long r = lo >> x;
        if (r) dr = __builtin_ctzll(r);
        else if (hi) dr = (64 - x) + __builtin_ctz(hi);
        unsigned long long lm = lo << (63 - x);      // bit x -> bit 63
        if (lm) dl = __builtin_clzll(lm);
    } else {
        int xh = x - 64;                             // 0..31
        unsigned int r = hi >> xh;
        if (r) dr = __builtin_ctz(r);
        unsigned int lmh = hi << (31 - xh);          // bit xh -> bit 31
        if (lmh) dl = __builtin_clz(lmh);
        else if (lo) dl = (xh + 1) + __builtin_clzll(lo);
    }
    return min(dl, dr);
}

// farthest |x - x'| over set bits of a non-empty 96-bit row.
__device__ __forceinline__ int farthest_dx(unsigned long long lo, unsigned int hi, int x) {
    int first = lo ? __builtin_ctzll(lo) : 64 + __builtin_ctz(hi);
    int last  = hi ? 95 - __builtin_clz(hi) : 63 - __builtin_clzll(lo);
    return max(x - first, last - x);
}

// squared distance from (y,x) to nearest set pixel in mask m. Expanding-ring
// search, exact: break when dy^2 >= best. Mask must be non-empty.
__device__ __forceinline__ int search2d(const unsigned int* m, int y, int x) {
    int best = INT_MAX;
    for (int dy = 0; dy < HH; ++dy) {
        if (dy * dy >= best) break;
        int yl = y - dy;
        if (yl >= 0) {
            unsigned long long lo = (unsigned long long)m[yl*WPR] |
                                    ((unsigned long long)m[yl*WPR+1] << 32);
            unsigned int hi = m[yl*WPR+2];
            if (lo | hi) {
                int dx = nearest_dx(lo, hi, x);
                best = min(best, dy*dy + dx*dx);
            }
        }
        int yh = y + dy;
        if (dy > 0 && yh < HH) {
            unsigned long long lo = (unsigned long long)m[yh*WPR] |
                                    ((unsigned long long)m[yh*WPR+1] << 32);
            unsigned int hi = m[yh*WPR+2];
            if (lo | hi) {
                int dx = nearest_dx(lo, hi, x);
                best = min(best, dy*dy + dx*dx);
            }
        }
    }
    return best;
}

// squared distance from (y,x) to FARTHEST set pixel (empty-set diameter
// fallback only; dead for 50%-dense random masks).
__device__ __forceinline__ int farthest2d(const unsigned int* m, int y, int x) {
    int best = 0;
    for (int yy = 0; yy < HH; ++yy) {
        unsigned long long lo = (unsigned long long)m[yy*WPR] |
                                ((unsigned long long)m[yy*WPR+1] << 32);
        unsigned int hi = m[yy*WPR+2];
        if (lo | hi) {
            int fd = farthest_dx(lo, hi, x);
            int dy = yy - y;
            best = max(best, dy*dy + fd*fd);
        }
    }
    return best;
}

// Single cooperative dispatch. Phase 1: 192 blocks (16 img x 12 stripes) each
// build their image's LDS bitmasks, search their 768-px stripe, and publish a
// per-block partial to a DISTINCT slot (agent-scope release store — no init
// required, so no memset dispatch and no dependence on ws poison value).
// grid.sync(). Phase 2: block 0 reduces 2x192 partials (acquire loads, G16-safe
// across XCD L2s) and stores the mean.
__global__ __launch_bounds__(TPB) void hausdorff_coop(const float* __restrict__ pred,
                                                      const float* __restrict__ targ,
                                                      int* __restrict__ partAB,
                                                      int* __restrict__ partBA,
                                                      float* __restrict__ out) {
    int blk    = blockIdx.x;
    int img    = blk / STRIPES;
    int stripe = blk - img * STRIPES;
    int tid    = threadIdx.x;

    __shared__ unsigned int sA[WPI], sB[WPI];
    __shared__ int redAB, redBA, fA, fB;
    if (tid == 0) { redAB = -1; redBA = -1; fA = 0; fB = 0; }
    __syncthreads();

    // ---- build masks: each thread packs 32-px words via 8 float4 loads
    for (int w = tid; w < 2 * WPI; w += TPB) {
        int set = w >= WPI;
        int ww  = set ? w - WPI : w;
        const float* src = (set ? targ : pred) + img * HN + 32 * ww;
        const float4* v4 = reinterpret_cast<const float4*>(src);
        unsigned int bits = 0;
        #pragma unroll
        for (int j = 0; j < 8; ++j) {
            float4 v = v4[j];
            if (v.x >= 0.5f) bits |= 1u << (4*j + 0);
            if (v.y >= 0.5f) bits |= 1u << (4*j + 1);
            if (v.z >= 0.5f) bits |= 1u << (4*j + 2);
            if (v.w >= 0.5f) bits |= 1u << (4*j + 3);
        }
        (set ? sB : sA)[ww] = bits;
        if (bits) { if (set) fB = 1; else fA = 1; }   // benign same-value race
    }
    __syncthreads();

    bool anyA = fA != 0, anyB = fB != 0;              // block-uniform
    int lAB = -1, lBA = -1;
    int y0 = stripe * ROWS_PER;

    if (anyA && anyB) {
        for (int k = 0; k < PX_PER; k += TPB) {
            int li = k + tid;
            int ry = li / HW;
            int y  = y0 + ry;
            int x  = li - ry * HW;
            bool a = (sA[y*WPR + (x>>5)] >> (x & 31)) & 1u;
            bool b = (sB[y*WPR + (x>>5)] >> (x & 31)) & 1u;
            if (a) lAB = max(lAB, search2d(sB, y, x));   // A-point -> set B
            if (b) lBA = max(lBA, search2d(sA, y, x));   // B-point -> set A
        }
    } else if (anyA) {        // B empty -> diameter of A (dead path, kept exact)
        for (int k = 0; k < PX_PER; k += TPB) {
            int li = k + tid;
            int ry = li / HW;
            int y  = y0 + ry;
            int x  = li - ry * HW;
            if ((sA[y*WPR + (x>>5)] >> (x & 31)) & 1u)
                lAB = max(lAB, farthest2d(sA, y, x));
        }
    } else if (anyB) {        // A empty -> diameter of B
        for (int k = 0; k < PX_PER; k += TPB) {
            int li = k + tid;
            int ry = li / HW;
            int y  = y0 + ry;
            int x  = li - ry * HW;
            if ((sB[y*WPR + (x>>5)] >> (x & 31)) & 1u)
                lBA = max(lBA, farthest2d(sB, y, x));
        }
    }

    // ---- wave shuffle max-reduce, then one LDS atomic per wave
    #pragma unroll
    for (int off = 32; off >= 1; off >>= 1) {
        lAB = max(lAB, __shfl_down(lAB, off, 64));
        lBA = max(lBA, __shfl_down(lBA, off, 64));
    }
    if ((tid & 63) == 0) {
        atomicMax(&redAB, lAB);
        atomicMax(&redBA, lBA);
    }
    __syncthreads();

    // ---- publish per-block partials to distinct slots (no init needed)
    if (tid == 0) {
        __hip_atomic_store(&partAB[blk], redAB, __ATOMIC_RELEASE, __HIP_MEMORY_SCOPE_AGENT);
        __hip_atomic_store(&partBA[blk], redBA, __ATOMIC_RELEASE, __HIP_MEMORY_SCOPE_AGENT);
    }

    cg::this_grid().sync();

    // ---- phase 2: block 0 reduces 12 stripes per image, computes the mean.
    // hd = sqrt(max(vAB, vBA, 0)) covers all empty-set rules: both non-empty ->
    // max of directed d^2; one empty -> its partial is -1, other holds diam^2;
    // both empty -> max(-1,-1,0) = 0.
    if (blk == 0) {
        float hd = 0.0f;
        if (tid < HB) {
            int vAB = -1, vBA = -1;
            #pragma unroll
            for (int s = 0; s < STRIPES; ++s) {
                vAB = max(vAB, __hip_atomic_load(&partAB[tid*STRIPES + s],
                                                 __ATOMIC_ACQUIRE, __HIP_MEMORY_SCOPE_AGENT));
                vBA = max(vBA, __hip_atomic_load(&partBA[tid*STRIPES + s],
                                                 __ATOMIC_ACQUIRE, __HIP_MEMORY_SCOPE_AGENT));
            }
            hd = sqrtf((float)max(max(vAB, vBA), 0));
        }
        if (tid < 64) {
            #pragma unroll
            for (int off = 8; off >= 1; off >>= 1)
                hd += __shfl_down(hd, off, 16);
            if (tid == 0) out[0] = hd * (1.0f / HB);
        }
    }
}

extern "C" void kernel_launch(void* const* d_in, const int* in_sizes, int n_in,
                              void* d_out, int out_size, void* d_ws, size_t ws_size,
                              hipStream_t stream) {
    const float* pred = (const float*)d_in[0];
    const float* targ = (const float*)d_in[1];
    float* out = (float*)d_out;

    // ws: partAB int[NBLK] | partBA int[NBLK] — plain-written, never read stale
    int* partAB = (int*)d_ws;
    int* partBA = partAB + NBLK;

    void* args[] = { (void*)&pred, (void*)&targ, (void*)&partAB, (void*)&partBA, (void*)&out };
    hipLaunchCooperativeKernel((const void*)hausdorff_coop, dim3(NBLK), dim3(TPB),
                               args, 0, stream);
}

// Round 9
// 64.554 us; speedup vs baseline: 1.6067x; 1.6067x over previous
//
#include <hip/hip_runtime.h>
#include <limits.h>

#define HB 16
#define HH 96
#define HW 96
#define HN (HH*HW)
#define WPR 3                   // u32 words per mask row
#define WPI (HH*WPR)            // 288 words per image mask
#define STRIPES 12
#define ROWS_PER (HH/STRIPES)   // 8 rows per stripe
#define PX_PER (ROWS_PER*HW)    // 768 px per stripe
#define TPB 256
#define NBLK (HB*STRIPES)       // 192 blocks

// nearest |x - x'| over set bits of a 96-bit row (lo = bits 0..63, hi = 64..95).
// Row must be non-empty; result <= 95. (Verified absmax=0 in R2-R4.)
__device__ __forceinline__ int nearest_dx(unsigned long long lo, unsigned int hi, int x) {
    int dr = 1 << 20, dl = 1 << 20;
    if (x < 64) {
        unsigned long long r = lo >> x;
        if (r) dr = __builtin_ctzll(r);
        else if (hi) dr = (64 - x) + __builtin_ctz(hi);
        unsigned long long lm = lo << (63 - x);      // bit x -> bit 63
        if (lm) dl = __builtin_clzll(lm);
    } else {
        int xh = x - 64;                             // 0..31
        unsigned int r = hi >> xh;
        if (r) dr = __builtin_ctz(r);
        unsigned int lmh = hi << (31 - xh);          // bit xh -> bit 31
        if (lmh) dl = __builtin_clz(lmh);
        else if (lo) dl = (xh + 1) + __builtin_clzll(lo);
    }
    return min(dl, dr);
}

// farthest |x - x'| over set bits of a non-empty 96-bit row.
__device__ __forceinline__ int farthest_dx(unsigned long long lo, unsigned int hi, int x) {
    int first = lo ? __builtin_ctzll(lo) : 64 + __builtin_ctz(hi);
    int last  = hi ? 95 - __builtin_clz(hi) : 63 - __builtin_clzll(lo);
    return max(x - first, last - x);
}

// squared distance from (y,x) to nearest set pixel in mask m. Expanding-ring
// search, exact: break when dy^2 >= best. Mask must be non-empty.
__device__ __forceinline__ int search2d(const unsigned int* m, int y, int x) {
    int best = INT_MAX;
    for (int dy = 0; dy < HH; ++dy) {
        if (dy * dy >= best) break;
        int yl = y - dy;
        if (yl >= 0) {
            unsigned long long lo = (unsigned long long)m[yl*WPR] |
                                    ((unsigned long long)m[yl*WPR+1] << 32);
            unsigned int hi = m[yl*WPR+2];
            if (lo | hi) {
                int dx = nearest_dx(lo, hi, x);
                best = min(best, dy*dy + dx*dx);
            }
        }
        int yh = y + dy;
        if (dy > 0 && yh < HH) {
            unsigned long long lo = (unsigned long long)m[yh*WPR] |
                                    ((unsigned long long)m[yh*WPR+1] << 32);
            unsigned int hi = m[yh*WPR+2];
            if (lo | hi) {
                int dx = nearest_dx(lo, hi, x);
                best = min(best, dy*dy + dx*dx);
            }
        }
    }
    return best;
}

// squared distance from (y,x) to FARTHEST set pixel (empty-set diameter
// fallback only; dead for 50%-dense random masks).
__device__ __forceinline__ int farthest2d(const unsigned int* m, int y, int x) {
    int best = 0;
    for (int yy = 0; yy < HH; ++yy) {
        unsigned long long lo = (unsigned long long)m[yy*WPR] |
                                ((unsigned long long)m[yy*WPR+1] << 32);
        unsigned int hi = m[yy*WPR+2];
        if (lo | hi) {
            int fd = farthest_dx(lo, hi, x);
            int dy = yy - y;
            best = max(best, dy*dy + fd*fd);
        }
    }
    return best;
}

// Dispatch 1: 192 blocks = 16 images x 12 stripes. Each block builds its
// image's LDS bitmasks (L2-served), searches its 768-px stripe, and publishes
// its partial to a DISTINCT slot with a plain store — no init, no atomics,
// no dependence on workspace poison value.
__global__ __launch_bounds__(TPB) void hausdorff_search(const float* __restrict__ pred,
                                                        const float* __restrict__ targ,
                                                        int* __restrict__ partAB,
                                                        int* __restrict__ partBA) {
    int blk    = blockIdx.x;
    int img    = blk / STRIPES;
    int stripe = blk - img * STRIPES;
    int tid    = threadIdx.x;

    __shared__ unsigned int sA[WPI], sB[WPI];
    __shared__ int redAB, redBA, fA, fB;
    if (tid == 0) { redAB = -1; redBA = -1; fA = 0; fB = 0; }
    __syncthreads();

    // ---- build masks: each thread packs 32-px words via 8 float4 loads
    for (int w = tid; w < 2 * WPI; w += TPB) {
        int set = w >= WPI;
        int ww  = set ? w - WPI : w;
        const float* src = (set ? targ : pred) + img * HN + 32 * ww;
        const float4* v4 = reinterpret_cast<const float4*>(src);
        unsigned int bits = 0;
        #pragma unroll
        for (int j = 0; j < 8; ++j) {
            float4 v = v4[j];
            if (v.x >= 0.5f) bits |= 1u << (4*j + 0);
            if (v.y >= 0.5f) bits |= 1u << (4*j + 1);
            if (v.z >= 0.5f) bits |= 1u << (4*j + 2);
            if (v.w >= 0.5f) bits |= 1u << (4*j + 3);
        }
        (set ? sB : sA)[ww] = bits;
        if (bits) { if (set) fB = 1; else fA = 1; }   // benign same-value race
    }
    __syncthreads();

    bool anyA = fA != 0, anyB = fB != 0;              // block-uniform
    int lAB = -1, lBA = -1;
    int y0 = stripe * ROWS_PER;

    if (anyA && anyB) {
        for (int k = 0; k < PX_PER; k += TPB) {
            int li = k + tid;
            int ry = li / HW;
            int y  = y0 + ry;
            int x  = li - ry * HW;
            bool a = (sA[y*WPR + (x>>5)] >> (x & 31)) & 1u;
            bool b = (sB[y*WPR + (x>>5)] >> (x & 31)) & 1u;
            if (a) lAB = max(lAB, search2d(sB, y, x));   // A-point -> set B
            if (b) lBA = max(lBA, search2d(sA, y, x));   // B-point -> set A
        }
    } else if (anyA) {        // B empty -> diameter of A (dead path, kept exact)
        for (int k = 0; k < PX_PER; k += TPB) {
            int li = k + tid;
            int ry = li / HW;
            int y  = y0 + ry;
            int x  = li - ry * HW;
            if ((sA[y*WPR + (x>>5)] >> (x & 31)) & 1u)
                lAB = max(lAB, farthest2d(sA, y, x));
        }
    } else if (anyB) {        // A empty -> diameter of B
        for (int k = 0; k < PX_PER; k += TPB) {
            int li = k + tid;
            int ry = li / HW;
            int y  = y0 + ry;
            int x  = li - ry * HW;
            if ((sB[y*WPR + (x>>5)] >> (x & 31)) & 1u)
                lBA = max(lBA, farthest2d(sB, y, x));
        }
    }

    // ---- wave shuffle max-reduce, then one LDS atomic per wave
    #pragma unroll
    for (int off = 32; off >= 1; off >>= 1) {
        lAB = max(lAB, __shfl_down(lAB, off, 64));
        lBA = max(lBA, __shfl_down(lBA, off, 64));
    }
    if ((tid & 63) == 0) {
        atomicMax(&redAB, lAB);
        atomicMax(&redBA, lBA);
    }
    __syncthreads();

    if (tid == 0) {           // distinct slot per block: plain store, init-free
        partAB[blk] = redAB;
        partBA[blk] = redBA;
    }
}

// Dispatch 2: one block reduces 12 stripes per image and stores the mean.
// hd = sqrt(max(vAB, vBA, 0)) covers all empty-set rules: both non-empty ->
// max of directed d^2; one empty -> its partial is -1, other holds diam^2;
// both empty -> max(-1,-1,0) = 0.
__global__ __launch_bounds__(64) void hausdorff_finalize(const int* __restrict__ partAB,
                                                         const int* __restrict__ partBA,
                                                         float* __restrict__ out) {
    int tid = threadIdx.x;
    float hd = 0.0f;
    if (tid < HB) {
        int vAB = -1, vBA = -1;
        #pragma unroll
        for (int s = 0; s < STRIPES; ++s) {
            vAB = max(vAB, partAB[tid*STRIPES + s]);
            vBA = max(vBA, partBA[tid*STRIPES + s]);
        }
        hd = sqrtf((float)max(max(vAB, vBA), 0));
    }
    #pragma unroll
    for (int off = 8; off >= 1; off >>= 1)
        hd += __shfl_down(hd, off, 16);
    if (tid == 0) out[0] = hd * (1.0f / HB);
}

extern "C" void kernel_launch(void* const* d_in, const int* in_sizes, int n_in,
                              void* d_out, int out_size, void* d_ws, size_t ws_size,
                              hipStream_t stream) {
    const float* pred = (const float*)d_in[0];
    const float* targ = (const float*)d_in[1];
    float* out = (float*)d_out;

    // ws: partAB int[NBLK] | partBA int[NBLK] — each slot plain-written by
    // exactly one block before being read; no initialization required.
    int* partAB = (int*)d_ws;
    int* partBA = partAB + NBLK;

    hausdorff_search<<<NBLK, TPB, 0, stream>>>(pred, targ, partAB, partBA);
    hausdorff_finalize<<<1, 64, 0, stream>>>(partAB, partBA, out);
}